// Round 4
// baseline (357.754 us; speedup 1.0000x reference)
//
#include <hip/hip_runtime.h>
#include <hip/hip_bf16.h>
#include <stdint.h>

typedef __attribute__((ext_vector_type(4))) float f32x4;
typedef __attribute__((ext_vector_type(8))) __bf16 bf16x8;
typedef __attribute__((ext_vector_type(8))) unsigned short u16x8;

__device__ __forceinline__ unsigned short f2bf(float f){
  uint32_t u = __builtin_bit_cast(uint32_t, f);
  u += 0x7FFFu + ((u >> 16) & 1u);
  return (unsigned short)(u >> 16);
}
__device__ __forceinline__ float bf2f(unsigned short h){
  return __builtin_bit_cast(float, ((uint32_t)h) << 16);
}
__device__ __forceinline__ float fast_exp2(float x){
#if __has_builtin(__builtin_amdgcn_exp2f)
  return __builtin_amdgcn_exp2f(x);
#else
  return exp2f(x);
#endif
}
__device__ __forceinline__ void gl_lds16(const unsigned short* g, unsigned short* l){
  __builtin_amdgcn_global_load_lds(
      (const __attribute__((address_space(1))) uint32_t*)g,
      (__attribute__((address_space(3))) uint32_t*)l, 16, 0, 0);
}

// ---------------- fp32 -> bf16 convert (weights) ----------------
__global__ __launch_bounds__(256) void f32_to_bf16(const float* __restrict__ in,
                                                   unsigned short* __restrict__ out, int n){
  int i = (blockIdx.x * 256 + threadIdx.x) * 8;
  if (i + 8 <= n) {
    float4 a = *(const float4*)&in[i];
    float4 b = *(const float4*)&in[i + 4];
    u16x8 o;
    o[0]=f2bf(a.x); o[1]=f2bf(a.y); o[2]=f2bf(a.z); o[3]=f2bf(a.w);
    o[4]=f2bf(b.x); o[5]=f2bf(b.y); o[6]=f2bf(b.z); o[7]=f2bf(b.w);
    *(u16x8*)&out[i] = o;
  }
}

// ---------------- GroupNorm stats ----------------
__global__ __launch_bounds__(256) void gn_stats(const float* __restrict__ x,
                                                float* __restrict__ stats){
  int grp = blockIdx.x; // b*32+g, 128 total
  const float* p = x + (size_t)grp * 65536;
  float s = 0.f, ss = 0.f;
  for (int i = threadIdx.x; i < 16384; i += 256) {
    float4 v = *(const float4*)(p + (size_t)i * 4);
    s  += v.x + v.y + v.z + v.w;
    ss += v.x*v.x + v.y*v.y + v.z*v.z + v.w*v.w;
  }
  for (int off = 32; off; off >>= 1) { s += __shfl_down(s, off); ss += __shfl_down(ss, off); }
  __shared__ float red[8];
  int w = threadIdx.x >> 6;
  if ((threadIdx.x & 63) == 0) { red[w] = s; red[w + 4] = ss; }
  __syncthreads();
  if (threadIdx.x == 0) {
    s  = red[0] + red[1] + red[2] + red[3];
    ss = red[4] + red[5] + red[6] + red[7];
    float mean = s * (1.f / 65536.f);
    float var  = ss * (1.f / 65536.f) - mean * mean;
    stats[grp * 2]     = mean;
    stats[grp * 2 + 1] = rsqrtf(var + 1e-6f);
  }
}

// ---------------- GN apply + transpose ----------------
__global__ __launch_bounds__(256) void gn_apply(const float* __restrict__ x,
                                                const float* __restrict__ stats,
                                                const float* __restrict__ gamma,
                                                const float* __restrict__ beta,
                                                unsigned short* __restrict__ hn_t){
  __shared__ float tile[32][33];
  int b  = blockIdx.z;
  int c0 = blockIdx.y * 32;
  int p0 = blockIdx.x * 32;
  int tx = threadIdx.x & 31, ty = threadIdx.x >> 5;
  const float* xb = x + (size_t)b * 512 * 4096;
#pragma unroll
  for (int i = 0; i < 32; i += 8)
    tile[ty + i][tx] = xb[(size_t)(c0 + ty + i) * 4096 + p0 + tx];
  __syncthreads();
  unsigned short* hb = hn_t + (size_t)b * 4096 * 512;
  int c = c0 + tx;
  float mean = stats[(b * 32 + (c >> 4)) * 2];
  float rstd = stats[(b * 32 + (c >> 4)) * 2 + 1];
  float ga = gamma[c], be = beta[c];
#pragma unroll
  for (int i = 0; i < 32; i += 8) {
    float v = tile[tx][ty + i];
    hb[(size_t)(p0 + ty + i) * 512 + c] = f2bf((v - mean) * rstd * ga + be);
  }
}

// ---------------- deep-phase GEMM: C[M,N] = A[M,K]*B[N,K]^T ----------------
// BM=256, BK=64, 512 threads = 8 waves (2 M-waves x 4 N-waves)
// BN=256: 4 phases/K-tile x 16 MFMA; BN=128: 2 phases x 16 MFMA
// MODE 1: +bias[col]->bf16 | 2: +bias[row]->bf16 | 3: mask*exp2(acc*sc)->bf16 + partials
// MODE 4: acc*rinv[row]->bf16 | 5: acc+resid+bias[col]->fp32 transposed
template<int MODE, int BN>
__device__ __forceinline__ void gemm_body(
    const unsigned short* __restrict__ A, const unsigned short* __restrict__ B,
    unsigned short* __restrict__ C, float* __restrict__ OUTF,
    const float* __restrict__ auxA, const float* __restrict__ auxB,
    float* __restrict__ auxW,
    int M, int N, int K, float scale,
    size_t sA, size_t sB, size_t sC, int gx, int gy)
{
  constexpr int NF = BN / 64;       // B n-frags per wave: 4 (BN=256) or 2 (BN=128)
  constexpr int CW = BN / 4;        // cols per wave
  constexpr int BL = BN / 64;       // B loads per thread per K-tile
  __shared__ __align__(16) unsigned short As[2][256 * 64];
  __shared__ __align__(16) unsigned short Bs[2][BN * 64];

  // XCD-aware bijective swizzle (nwg % 8 == 0 for all launches)
  const int lin = blockIdx.x;
  const int nwg = gridDim.x;
  const int wg = ((lin & 7) * (nwg >> 3)) + (lin >> 3);
  const int bx = wg % gx;
  const int t2 = wg / gx;
  const int by = t2 % gy;
  const int bz = t2 / gy;

  const unsigned short* Ab = A + (size_t)bz * sA;
  const unsigned short* Bb = B + (size_t)bz * sB;
  const int brow = bx * 256;
  const int bcol = by * BN;
  const int t = threadIdx.x;
  const int lane = t & 63;
  const int wid = t >> 6;
  const int wr = wid >> 2;          // 0..1  (128 rows each)
  const int wc = wid & 3;           // 0..3  (CW cols each)

  const f32x4 zero = {0.f, 0.f, 0.f, 0.f};
  f32x4 acc[8][NF];
#pragma unroll
  for (int m = 0; m < 8; m++)
#pragma unroll
    for (int n = 0; n < NF; n++) acc[m][n] = zero;

  const int la = lane & 15;
  const int lk = lane >> 4;         // 0..3
  const int xorv = la >> 1;         // per-lane slot XOR (row>>1)&7

  auto STAGE = [&](int kt, int buf) {
    const int ko = kt * 64;
#pragma unroll
    for (int j = 0; j < 4; ++j) {
      const int c = j * 512 + t;
      const int r = c >> 3;
      const int g = (c & 7) ^ ((r >> 1) & 7);
      gl_lds16(Ab + (size_t)(brow + r) * K + ko + g * 8, &As[buf][c * 8]);
    }
#pragma unroll
    for (int j = 0; j < BL; ++j) {
      const int c = j * 512 + t;
      const int r = c >> 3;
      const int g = (c & 7) ^ ((r >> 1) & 7);
      gl_lds16(Bb + (size_t)(bcol + r) * K + ko + g * 8, &Bs[buf][c * 8]);
    }
  };
  auto LDA = [&](int buf, int m, int kst) -> bf16x8 {
    const int row = wr * 128 + m * 16 + la;
    const int slot = (kst * 4 + lk) ^ xorv;
    return __builtin_bit_cast(bf16x8, *(const u16x8*)&As[buf][row * 64 + slot * 8]);
  };
  auto LDB = [&](int buf, int n, int kst) -> bf16x8 {
    const int row = wc * CW + n * 16 + la;
    const int slot = (kst * 4 + lk) ^ xorv;
    return __builtin_bit_cast(bf16x8, *(const u16x8*)&Bs[buf][row * 64 + slot * 8]);
  };

  const int nk = K >> 6;
  STAGE(0, 0);
  for (int kt = 0; kt < nk; ++kt) {
    const int buf = kt & 1;
    if (kt + 1 < nk) {
      STAGE(kt + 1, buf ^ 1);
      __builtin_amdgcn_sched_barrier(0);
      if constexpr (BN == 256) asm volatile("s_waitcnt vmcnt(8)" ::: "memory");
      else                     asm volatile("s_waitcnt vmcnt(6)" ::: "memory");
      __builtin_amdgcn_sched_barrier(0);
    } else {
      asm volatile("s_waitcnt vmcnt(0)" ::: "memory");
      __builtin_amdgcn_sched_barrier(0);
    }
    __builtin_amdgcn_s_barrier();

    if constexpr (BN == 256) {
      bf16x8 bq[4];
#pragma unroll
      for (int ph = 0; ph < 4; ++ph) {
        const int kst = ph >> 1, mh = ph & 1;
        if (mh == 0) {
#pragma unroll
          for (int n = 0; n < 4; n++) bq[n] = LDB(buf, n, kst);
        }
        bf16x8 aq[4];
#pragma unroll
        for (int i = 0; i < 4; i++) aq[i] = LDA(buf, mh * 4 + i, kst);
        asm volatile("s_waitcnt lgkmcnt(0)" ::: "memory");
        __builtin_amdgcn_sched_barrier(0);
        __builtin_amdgcn_s_setprio(1);
#pragma unroll
        for (int i = 0; i < 4; i++)
#pragma unroll
          for (int n = 0; n < 4; n++)
            acc[mh * 4 + i][n] = __builtin_amdgcn_mfma_f32_16x16x32_bf16(aq[i], bq[n], acc[mh * 4 + i][n], 0, 0, 0);
        __builtin_amdgcn_s_setprio(0);
        __builtin_amdgcn_sched_barrier(0);
        __builtin_amdgcn_s_barrier();
      }
    } else {
#pragma unroll
      for (int ph = 0; ph < 2; ++ph) {
        bf16x8 bq[2];
#pragma unroll
        for (int n = 0; n < 2; n++) bq[n] = LDB(buf, n, ph);
        bf16x8 aq[8];
#pragma unroll
        for (int m = 0; m < 8; m++) aq[m] = LDA(buf, m, ph);
        asm volatile("s_waitcnt lgkmcnt(0)" ::: "memory");
        __builtin_amdgcn_sched_barrier(0);
        __builtin_amdgcn_s_setprio(1);
#pragma unroll
        for (int m = 0; m < 8; m++)
#pragma unroll
          for (int n = 0; n < 2; n++)
            acc[m][n] = __builtin_amdgcn_mfma_f32_16x16x32_bf16(aq[m], bq[n], acc[m][n], 0, 0, 0);
        __builtin_amdgcn_s_setprio(0);
        __builtin_amdgcn_sched_barrier(0);
        __builtin_amdgcn_s_barrier();
      }
    }
  }

  // epilogue: C/D layout col=lane&15, row=(lane>>4)*4+j
  const int cl = la;
  const int rg = lk * 4;

  if (MODE == 1 || MODE == 2) {
    unsigned short* Cb = C + (size_t)bz * sC;
#pragma unroll
    for (int m = 0; m < 8; m++) {
#pragma unroll
      for (int n = 0; n < NF; n++) {
        const int col = bcol + wc * CW + n * 16 + cl;
        const float bcv = (MODE == 1) ? auxA[col] : 0.f;
#pragma unroll
        for (int j = 0; j < 4; j++) {
          const int row = brow + wr * 128 + m * 16 + rg + j;
          float v = acc[m][n][j] + bcv + ((MODE == 2) ? auxA[row] : 0.f);
          Cb[(size_t)row * N + col] = f2bf(v);
        }
      }
    }
  } else if (MODE == 3) {
    unsigned short* Cb = C + (size_t)bz * sC;
    const float* maskb = auxA + (size_t)bz * 4096;
    float* partb = auxW + ((size_t)bz * 64 + (size_t)(by * 4 + wc)) * M;
    const float sc2 = scale * 1.4426950408889634f;
    f32x4 rs[8];
#pragma unroll
    for (int m = 0; m < 8; m++) rs[m] = zero;
#pragma unroll
    for (int m = 0; m < 8; m++) {
#pragma unroll
      for (int n = 0; n < NF; n++) {
        const int col = bcol + wc * CW + n * 16 + cl;
        const float mk = maskb[col];
#pragma unroll
        for (int j = 0; j < 4; j++) {
          const int row = brow + wr * 128 + m * 16 + rg + j;
          float v = mk * fast_exp2(acc[m][n][j] * sc2);
          rs[m][j] += v;
          Cb[(size_t)row * N + col] = f2bf(v);
        }
      }
    }
#pragma unroll
    for (int off = 1; off < 16; off <<= 1)
#pragma unroll
      for (int m = 0; m < 8; m++) {
#pragma unroll
        for (int j = 0; j < 4; j++) rs[m][j] += __shfl_xor(rs[m][j], off);
      }
    if (cl == 0) {
#pragma unroll
      for (int m = 0; m < 8; m++) {
        float4 v = make_float4(rs[m][0], rs[m][1], rs[m][2], rs[m][3]);
        *(float4*)&partb[brow + wr * 128 + m * 16 + rg] = v;
      }
    }
  } else if (MODE == 4) {
    unsigned short* Cb = C + (size_t)bz * sC;
    const float* rb = auxA + (size_t)bz * 4096;
#pragma unroll
    for (int m = 0; m < 8; m++) {
      const float4 ri = *(const float4*)&rb[brow + wr * 128 + m * 16 + rg];
      const float riv[4] = {ri.x, ri.y, ri.z, ri.w};
#pragma unroll
      for (int n = 0; n < NF; n++) {
        const int col = bcol + wc * CW + n * 16 + cl;
#pragma unroll
        for (int j = 0; j < 4; j++) {
          const int row = brow + wr * 128 + m * 16 + rg + j;
          Cb[(size_t)row * N + col] = f2bf(acc[m][n][j] * riv[j]);
        }
      }
    }
  } else { // MODE 5
#pragma unroll
    for (int m = 0; m < 8; m++) {
      const int row = brow + wr * 128 + m * 16 + rg;
      const int bb = row >> 12;
      const int p  = row & 4095;
#pragma unroll
      for (int n = 0; n < NF; n++) {
        const int col = bcol + wc * CW + n * 16 + cl;
        const size_t idx = ((size_t)bb * 512 + col) * 4096 + p;
        const float4 xv = *(const float4*)&auxA[idx];
        const float bv = auxB[col];
        float4 ov;
        ov.x = acc[m][n][0] + xv.x + bv;
        ov.y = acc[m][n][1] + xv.y + bv;
        ov.z = acc[m][n][2] + xv.z + bv;
        ov.w = acc[m][n][3] + xv.w + bv;
        *(float4*)&OUTF[idx] = ov;
      }
    }
  }
}

#define GEMM_ARGS const unsigned short* A, const unsigned short* B, unsigned short* C, \
                  float* OUTF, const float* auxA, const float* auxB, float* auxW, \
                  int M, int N, int K, float scale, size_t sA, size_t sB, size_t sC, int gx, int gy
#define GEMM_PASS A, B, C, OUTF, auxA, auxB, auxW, M, N, K, scale, sA, sB, sC, gx, gy

__global__ __launch_bounds__(512, 2) void k_qkproj(GEMM_ARGS){ gemm_body<1, 128>(GEMM_PASS); }
__global__ __launch_bounds__(512, 2) void k_vproj (GEMM_ARGS){ gemm_body<2, 128>(GEMM_PASS); }
__global__ __launch_bounds__(512, 2) void k_scores(GEMM_ARGS){ gemm_body<3, 256>(GEMM_PASS); }
__global__ __launch_bounds__(512, 2) void k_pv    (GEMM_ARGS){ gemm_body<4, 128>(GEMM_PASS); }
__global__ __launch_bounds__(512, 2) void k_oproj (GEMM_ARGS){ gemm_body<5, 128>(GEMM_PASS); }

// ---------------- rowsum reduce ----------------
__global__ __launch_bounds__(256) void rowsum_inv(const float* __restrict__ partial,
                                                  float* __restrict__ rinv){
  const int idx = blockIdx.x * 256 + threadIdx.x;   // 16384
  const int b = idx >> 12, q = idx & 4095;
  const float* p = partial + ((size_t)b * 64) * 4096 + q;
  float s = 0.f;
#pragma unroll
  for (int i = 0; i < 64; i++) s += p[(size_t)i * 4096];
  rinv[idx] = 1.f / s;
}

extern "C" void kernel_launch(void* const* d_in, const int* in_sizes, int n_in,
                              void* d_out, int out_size, void* d_ws, size_t ws_size,
                              hipStream_t stream) {
  const float* x     = (const float*)d_in[0];
  const float* mask  = (const float*)d_in[1];
  const float* gamma = (const float*)d_in[2];
  const float* beta  = (const float*)d_in[3];
  const float* Wq    = (const float*)d_in[4];
  const float* bq    = (const float*)d_in[5];
  const float* Wk    = (const float*)d_in[6];
  const float* bk    = (const float*)d_in[7];
  const float* Wv    = (const float*)d_in[8];
  const float* bv    = (const float*)d_in[9];
  const float* Wo    = (const float*)d_in[10];
  const float* bo    = (const float*)d_in[11];
  float* out = (float*)d_out;

  size_t off = 0;
  auto nxt = [&](size_t bytes) -> void* {
    void* p = (char*)d_ws + off;
    off += (bytes + 255) & ~(size_t)255;
    return p;
  };
  float* stats          = (float*)nxt(256 * sizeof(float));
  float* partial        = (float*)nxt((size_t)4 * 64 * 4096 * 4);
  float* rinv           = (float*)nxt((size_t)16384 * 4);
  unsigned short* Wqb   = (unsigned short*)nxt((size_t)512 * 512 * 2);
  unsigned short* Wkb   = (unsigned short*)nxt((size_t)512 * 512 * 2);
  unsigned short* Wvb   = (unsigned short*)nxt((size_t)512 * 512 * 2);
  unsigned short* Wob   = (unsigned short*)nxt((size_t)512 * 512 * 2);
  unsigned short* hnt   = (unsigned short*)nxt((size_t)16384 * 512 * 2);
  unsigned short* qt    = (unsigned short*)nxt((size_t)16384 * 512 * 2);
  unsigned short* ktb   = (unsigned short*)nxt((size_t)16384 * 512 * 2);
  unsigned short* vcm   = (unsigned short*)nxt((size_t)16384 * 512 * 2);
  unsigned short* ot    = (unsigned short*)nxt((size_t)16384 * 512 * 2);
  unsigned short* P     = (unsigned short*)nxt((size_t)4 * 4096 * 4096 * 2);

  f32_to_bf16<<<128, 256, 0, stream>>>(Wq, Wqb, 262144);
  f32_to_bf16<<<128, 256, 0, stream>>>(Wk, Wkb, 262144);
  f32_to_bf16<<<128, 256, 0, stream>>>(Wv, Wvb, 262144);
  f32_to_bf16<<<128, 256, 0, stream>>>(Wo, Wob, 262144);

  gn_stats<<<128, 256, 0, stream>>>(x, stats);
  gn_apply<<<dim3(128, 16, 4), 256, 0, stream>>>(x, stats, gamma, beta, hnt);

  // Q, K: [16384,512] = hn_t x W^T (+ per-col bias); gx=64, gy=4, gz=1 -> 256
  k_qkproj<<<256, 512, 0, stream>>>(hnt, Wqb, qt, nullptr, bq, nullptr, nullptr,
                                    16384, 512, 512, 1.f, 0, 0, 0, 64, 4);
  k_qkproj<<<256, 512, 0, stream>>>(hnt, Wkb, ktb, nullptr, bk, nullptr, nullptr,
                                    16384, 512, 512, 1.f, 0, 0, 0, 64, 4);
  // V channel-major: v_cm[b][c][p] (+ per-row bias); gx=2, gy=32, gz=4 -> 256
  k_vproj<<<256, 512, 0, stream>>>(Wvb, hnt, vcm, nullptr, bv, nullptr, nullptr,
                                   512, 4096, 512, 1.f,
                                   0, (size_t)4096 * 512, (size_t)512 * 4096, 2, 32);
  // scores -> P_un = mask*exp(s*scale) (bf16) + row partial sums; gx=16, gy=16, gz=4 -> 1024
  k_scores<<<1024, 512, 0, stream>>>(qt, ktb, P, nullptr, mask, nullptr, partial,
                                     4096, 4096, 512, 0.044194173824159216f,
                                     (size_t)4096 * 512, (size_t)4096 * 512,
                                     (size_t)4096 * 4096, 16, 16);
  rowsum_inv<<<64, 256, 0, stream>>>(partial, rinv);
  // PV: ot[b][qi][c] = (P_un x v_cm^T) * rinv[qi]; gx=16, gy=4, gz=4 -> 256
  k_pv<<<256, 512, 0, stream>>>(P, vcm, ot, nullptr, rinv, nullptr, nullptr,
                                4096, 512, 4096, 1.f,
                                (size_t)4096 * 4096, (size_t)512 * 4096,
                                (size_t)4096 * 512, 16, 4);
  // O-projection + residual + bias -> fp32 out; gx=64, gy=4, gz=1 -> 256
  k_oproj<<<256, 512, 0, stream>>>(ot, Wob, nullptr, out, x, bo, nullptr,
                                   16384, 512, 512, 1.f, 0, 0, 0, 64, 4);
}

// Round 5
// 278.871 us; speedup vs baseline: 1.2829x; 1.2829x over previous
//
#include <hip/hip_runtime.h>
#include <hip/hip_bf16.h>
#include <stdint.h>

typedef __attribute__((ext_vector_type(4))) float f32x4;
typedef __attribute__((ext_vector_type(8))) __bf16 bf16x8;
typedef __attribute__((ext_vector_type(8))) unsigned short u16x8;

__device__ __forceinline__ unsigned short f2bf(float f){
  uint32_t u = __builtin_bit_cast(uint32_t, f);
  u += 0x7FFFu + ((u >> 16) & 1u);
  return (unsigned short)(u >> 16);
}
__device__ __forceinline__ float bf2f(unsigned short h){
  return __builtin_bit_cast(float, ((uint32_t)h) << 16);
}
__device__ __forceinline__ float fast_exp2(float x){
#if __has_builtin(__builtin_amdgcn_exp2f)
  return __builtin_amdgcn_exp2f(x);
#else
  return exp2f(x);
#endif
}
__device__ __forceinline__ void gl_lds16(const unsigned short* g, unsigned short* l){
  __builtin_amdgcn_global_load_lds(
      (const __attribute__((address_space(1))) uint32_t*)g,
      (__attribute__((address_space(3))) uint32_t*)l, 16, 0, 0);
}

// ---------------- fp32 -> bf16 convert (all 4 weights, one launch) ----------------
__global__ __launch_bounds__(256) void conv4(const float* __restrict__ a, const float* __restrict__ b,
                                             const float* __restrict__ c, const float* __restrict__ d,
                                             unsigned short* __restrict__ oa, unsigned short* __restrict__ ob,
                                             unsigned short* __restrict__ oc, unsigned short* __restrict__ od){
  const int bid = blockIdx.x;            // 512 blocks; 128 per weight
  const int sel = bid >> 7;
  const float* in = sel == 0 ? a : sel == 1 ? b : sel == 2 ? c : d;
  unsigned short* out = sel == 0 ? oa : sel == 1 ? ob : sel == 2 ? oc : od;
  const int i = ((bid & 127) * 256 + threadIdx.x) * 8;
  float4 v0 = *(const float4*)&in[i];
  float4 v1 = *(const float4*)&in[i + 4];
  u16x8 o;
  o[0]=f2bf(v0.x); o[1]=f2bf(v0.y); o[2]=f2bf(v0.z); o[3]=f2bf(v0.w);
  o[4]=f2bf(v1.x); o[5]=f2bf(v1.y); o[6]=f2bf(v1.z); o[7]=f2bf(v1.w);
  *(u16x8*)&out[i] = o;
}

// ---------------- GroupNorm stats, 2-stage ----------------
__global__ __launch_bounds__(256) void gn_stats1(const float* __restrict__ x,
                                                 float* __restrict__ part){
  const int bid = blockIdx.x;            // 1024 segments of 8192 floats
  const float* p = x + (size_t)bid * 8192;
  float s = 0.f, ss = 0.f;
  for (int i = threadIdx.x; i < 2048; i += 256) {
    float4 v = *(const float4*)(p + (size_t)i * 4);
    s  += v.x + v.y + v.z + v.w;
    ss += v.x*v.x + v.y*v.y + v.z*v.z + v.w*v.w;
  }
  for (int off = 32; off; off >>= 1) { s += __shfl_down(s, off); ss += __shfl_down(ss, off); }
  __shared__ float red[8];
  int w = threadIdx.x >> 6;
  if ((threadIdx.x & 63) == 0) { red[w] = s; red[w + 4] = ss; }
  __syncthreads();
  if (threadIdx.x == 0) {
    part[bid * 2]     = red[0] + red[1] + red[2] + red[3];
    part[bid * 2 + 1] = red[4] + red[5] + red[6] + red[7];
  }
}
__global__ __launch_bounds__(128) void gn_stats2(const float* __restrict__ part,
                                                 float* __restrict__ stats){
  const int g = threadIdx.x;             // 128 groups
  float s = 0.f, ss = 0.f;
#pragma unroll
  for (int i = 0; i < 8; i++) { s += part[(g * 8 + i) * 2]; ss += part[(g * 8 + i) * 2 + 1]; }
  float mean = s * (1.f / 65536.f);
  float var  = ss * (1.f / 65536.f) - mean * mean;
  stats[g * 2]     = mean;
  stats[g * 2 + 1] = rsqrtf(var + 1e-6f);
}

// ---------------- GN apply + transpose ----------------
__global__ __launch_bounds__(256) void gn_apply(const float* __restrict__ x,
                                                const float* __restrict__ stats,
                                                const float* __restrict__ gamma,
                                                const float* __restrict__ beta,
                                                unsigned short* __restrict__ hn_t){
  __shared__ float tile[32][33];
  int b  = blockIdx.z;
  int c0 = blockIdx.y * 32;
  int p0 = blockIdx.x * 32;
  int tx = threadIdx.x & 31, ty = threadIdx.x >> 5;
  const float* xb = x + (size_t)b * 512 * 4096;
#pragma unroll
  for (int i = 0; i < 32; i += 8)
    tile[ty + i][tx] = xb[(size_t)(c0 + ty + i) * 4096 + p0 + tx];
  __syncthreads();
  unsigned short* hb = hn_t + (size_t)b * 4096 * 512;
  int c = c0 + tx;
  float mean = stats[(b * 32 + (c >> 4)) * 2];
  float rstd = stats[(b * 32 + (c >> 4)) * 2 + 1];
  float ga = gamma[c], be = beta[c];
#pragma unroll
  for (int i = 0; i < 32; i += 8) {
    float v = tile[tx][ty + i];
    hb[(size_t)(p0 + ty + i) * 512 + c] = f2bf((v - mean) * rstd * ga + be);
  }
}

// ---------------- deep-phase GEMM: C[M,N] = A[M,K]*B[N,K]^T ----------------
// BM=256, BK=64, 512 threads = 8 waves (2M x 4N).
// BN=256: wave out 128x64, 4 phases/K-tile; BN=128: wave out 128x32, 2 phases/K-tile.
// Stage units of 16KB: A-unit h = rows {mh-quadrant h for both wr halves};
// B-unit h = rows {nh-quadrant h for all wc} (BN=256) / full B-tile (BN=128).
// Phase: vmcnt(counted); s_barrier; ds_read; stage 1 unit of tile j+1;
//        lgkmcnt(0); sched_barrier; setprio(1); 16 MFMA; setprio(0).
template<int MODE, int BN>
__device__ __forceinline__ void gemm_body(
    const unsigned short* __restrict__ A, const unsigned short* __restrict__ B,
    unsigned short* __restrict__ C, float* __restrict__ OUTF,
    const float* __restrict__ auxA, const float* __restrict__ auxB,
    float* __restrict__ auxW,
    int M, int N, int K, float scale,
    size_t sA, size_t sB, size_t sC, int gx, int gy)
{
  constexpr int NF = BN / 64;       // 4 or 2
  constexpr int CW = BN / 4;        // 64 or 32
  __shared__ __align__(16) unsigned short As[4 * 8192];                 // 64 KB
  __shared__ __align__(16) unsigned short Bs[(BN == 256 ? 4 : 2) * 8192];

  // XCD-aware bijective swizzle (nwg % 8 == 0 for all launches)
  const int lin = blockIdx.x;
  const int nwg = gridDim.x;
  const int wg = ((lin & 7) * (nwg >> 3)) + (lin >> 3);
  const int bx = wg % gx;
  const int t2 = wg / gx;
  const int by = t2 % gy;
  const int bz = t2 / gy;

  const unsigned short* Ab = A + (size_t)bz * sA;
  const unsigned short* Bb = B + (size_t)bz * sB;
  const int brow = bx * 256;
  const int bcol = by * BN;
  const int t = threadIdx.x;
  const int lane = t & 63;
  const int wid = t >> 6;
  const int wr = wid >> 2;          // 0..1
  const int wc = wid & 3;           // 0..3
  const int la = lane & 15;
  const int lk = lane >> 4;         // 0..3
  const int axr = la >> 1;          // read-side slot XOR

  const f32x4 zero = {0.f, 0.f, 0.f, 0.f};
  f32x4 acc[8][NF];
#pragma unroll
  for (int m = 0; m < 8; m++)
#pragma unroll
    for (int n = 0; n < NF; n++) acc[m][n] = zero;

  const int ru0 = t >> 3, s0 = t & 7;
  const int gx0 = s0 ^ ((ru0 >> 1) & 7);     // write-side XOR (same for ru0 and 64+ru0)

  auto stageA = [&](int kt, int h) {
    unsigned short* base = As + ((kt & 1) * 2 + h) * 8192;
    const size_t ko = (size_t)kt * 64;
    gl_lds16(Ab + (size_t)(brow + h * 64 + ru0) * K + ko + gx0 * 8, base + t * 8);
    gl_lds16(Ab + (size_t)(brow + 128 + h * 64 + ru0) * K + ko + gx0 * 8, base + 4096 + t * 8);
  };
  auto stageB = [&](int kt, int h) {    // BN==256
    unsigned short* base = Bs + ((kt & 1) * 2 + h) * 8192;
    const size_t ko = (size_t)kt * 64;
    const int r0 = ((ru0 >> 5) << 6) + h * 32 + (ru0 & 31);
    gl_lds16(Bb + (size_t)(bcol + r0) * K + ko + gx0 * 8, base + t * 8);
    const int r1 = (((64 + ru0) >> 5) << 6) + h * 32 + (ru0 & 31);
    gl_lds16(Bb + (size_t)(bcol + r1) * K + ko + gx0 * 8, base + 4096 + t * 8);
  };
  auto stageBf = [&](int kt) {          // BN==128, full tile
    unsigned short* base = Bs + (kt & 1) * 8192;
    const size_t ko = (size_t)kt * 64;
    gl_lds16(Bb + (size_t)(bcol + ru0) * K + ko + gx0 * 8, base + t * 8);
    gl_lds16(Bb + (size_t)(bcol + 64 + ru0) * K + ko + gx0 * 8, base + 4096 + t * 8);
  };
  auto LDA = [&](int db, int mh, int i, int kst) -> bf16x8 {
    const int ru = wr * 64 + i * 16 + la;
    const int slot = ((kst << 2) | lk) ^ axr;
    return __builtin_bit_cast(bf16x8, *(const u16x8*)&As[(db * 2 + mh) * 8192 + ru * 64 + slot * 8]);
  };
  auto LDB = [&](int db, int nh, int n2, int kst) -> bf16x8 {
    const int ru = wc * 32 + n2 * 16 + la;
    const int slot = ((kst << 2) | lk) ^ axr;
    const int base = (BN == 256 ? (db * 2 + nh) : db) * 8192;
    return __builtin_bit_cast(bf16x8, *(const u16x8*)&Bs[base + ru * 64 + slot * 8]);
  };

#define DSR(mh, nh) \
  bf16x8 aq[4][2], bq[2][2]; \
  _Pragma("unroll") for (int i = 0; i < 4; ++i) { aq[i][0] = LDA(db, mh, i, 0); aq[i][1] = LDA(db, mh, i, 1); } \
  _Pragma("unroll") for (int n2 = 0; n2 < 2; ++n2) { bq[n2][0] = LDB(db, nh, n2, 0); bq[n2][1] = LDB(db, nh, n2, 1); }

#define MM(mh, nh) \
  asm volatile("s_waitcnt lgkmcnt(0)" ::: "memory"); \
  __builtin_amdgcn_sched_barrier(0); \
  __builtin_amdgcn_s_setprio(1); \
  _Pragma("unroll") for (int i = 0; i < 4; ++i) \
    _Pragma("unroll") for (int n2 = 0; n2 < 2; ++n2) { \
      acc[(mh)*4+i][(nh)*2+n2] = __builtin_amdgcn_mfma_f32_16x16x32_bf16(aq[i][0], bq[n2][0], acc[(mh)*4+i][(nh)*2+n2], 0, 0, 0); \
      acc[(mh)*4+i][(nh)*2+n2] = __builtin_amdgcn_mfma_f32_16x16x32_bf16(aq[i][1], bq[n2][1], acc[(mh)*4+i][(nh)*2+n2], 0, 0, 0); } \
  __builtin_amdgcn_s_setprio(0); \
  __builtin_amdgcn_sched_barrier(0);

#define PHASE(VMS, mh, nh, STG) do { \
  asm volatile("s_waitcnt vmcnt(" VMS ")" ::: "memory"); \
  __builtin_amdgcn_s_barrier(); \
  DSR(mh, nh); \
  STG; \
  MM(mh, nh); \
} while (0)

  const int nk = K >> 6;
  if constexpr (BN == 256) {
    stageA(0, 0); stageB(0, 0); stageA(0, 1); stageB(0, 1);
    for (int j = 0; j < nk - 1; ++j) {
      const int db = j & 1;
      PHASE("4", 0, 0, { stageA(j + 1, 0); });
      PHASE("4", 1, 0, { stageB(j + 1, 0); });
      PHASE("4", 1, 1, { stageA(j + 1, 1); });
      PHASE("6", 0, 1, { stageB(j + 1, 1); });
    }
    {
      const int db = (nk - 1) & 1;
      asm volatile("s_waitcnt vmcnt(0)" ::: "memory");
      __builtin_amdgcn_s_barrier();
      { DSR(0, 0); MM(0, 0); }
      { DSR(1, 0); MM(1, 0); }
      { DSR(1, 1); MM(1, 1); }
      { DSR(0, 1); MM(0, 1); }
    }
  } else {
    stageA(0, 0); stageBf(0); stageA(0, 1);
    for (int j = 0; j < nk - 1; ++j) {
      const int db = j & 1;
      PHASE("2", 0, 0, { stageA(j + 1, 0); stageBf(j + 1); });
      PHASE("4", 1, 0, { stageA(j + 1, 1); });
    }
    {
      const int db = (nk - 1) & 1;
      asm volatile("s_waitcnt vmcnt(0)" ::: "memory");
      __builtin_amdgcn_s_barrier();
      { DSR(0, 0); MM(0, 0); }
      { DSR(1, 0); MM(1, 0); }
    }
  }
#undef PHASE
#undef MM
#undef DSR

  // epilogue: C/D layout col=lane&15, row=(lane>>4)*4+j
  const int cl = la;
  const int rg = lk * 4;

  if (MODE == 1 || MODE == 2) {
    unsigned short* Cb = C + (size_t)bz * sC;
#pragma unroll
    for (int m = 0; m < 8; m++) {
#pragma unroll
      for (int n = 0; n < NF; n++) {
        const int col = bcol + wc * CW + n * 16 + cl;
        const float bcv = (MODE == 1) ? auxA[col] : 0.f;
#pragma unroll
        for (int j = 0; j < 4; j++) {
          const int row = brow + wr * 128 + m * 16 + rg + j;
          float v = acc[m][n][j] + bcv + ((MODE == 2) ? auxA[row] : 0.f);
          Cb[(size_t)row * N + col] = f2bf(v);
        }
      }
    }
  } else if (MODE == 3) {
    unsigned short* Cb = C + (size_t)bz * sC;
    const float* maskb = auxA + (size_t)bz * 4096;
    float* partb = auxW + ((size_t)bz * 64 + (size_t)(by * 4 + wc)) * M;
    const float sc2 = scale * 1.4426950408889634f;
    f32x4 rs[8];
#pragma unroll
    for (int m = 0; m < 8; m++) rs[m] = zero;
#pragma unroll
    for (int m = 0; m < 8; m++) {
#pragma unroll
      for (int n = 0; n < NF; n++) {
        const int col = bcol + wc * CW + n * 16 + cl;
        const float mk = maskb[col];
#pragma unroll
        for (int j = 0; j < 4; j++) {
          const int row = brow + wr * 128 + m * 16 + rg + j;
          float v = mk * fast_exp2(acc[m][n][j] * sc2);
          rs[m][j] += v;
          Cb[(size_t)row * N + col] = f2bf(v);
        }
      }
    }
#pragma unroll
    for (int off = 1; off < 16; off <<= 1)
#pragma unroll
      for (int m = 0; m < 8; m++) {
#pragma unroll
        for (int j = 0; j < 4; j++) rs[m][j] += __shfl_xor(rs[m][j], off);
      }
    if (cl == 0) {
#pragma unroll
      for (int m = 0; m < 8; m++) {
        float4 v = make_float4(rs[m][0], rs[m][1], rs[m][2], rs[m][3]);
        *(float4*)&partb[brow + wr * 128 + m * 16 + rg] = v;
      }
    }
  } else if (MODE == 4) {
    unsigned short* Cb = C + (size_t)bz * sC;
    const float* rb = auxA + (size_t)bz * 4096;
#pragma unroll
    for (int m = 0; m < 8; m++) {
      const float4 ri = *(const float4*)&rb[brow + wr * 128 + m * 16 + rg];
      const float riv[4] = {ri.x, ri.y, ri.z, ri.w};
#pragma unroll
      for (int n = 0; n < NF; n++) {
        const int col = bcol + wc * CW + n * 16 + cl;
#pragma unroll
        for (int j = 0; j < 4; j++) {
          const int row = brow + wr * 128 + m * 16 + rg + j;
          Cb[(size_t)row * N + col] = f2bf(acc[m][n][j] * riv[j]);
        }
      }
    }
  } else { // MODE 5
#pragma unroll
    for (int m = 0; m < 8; m++) {
      const int row = brow + wr * 128 + m * 16 + rg;
      const int bb = row >> 12;
      const int p  = row & 4095;
#pragma unroll
      for (int n = 0; n < NF; n++) {
        const int col = bcol + wc * CW + n * 16 + cl;
        const size_t idx = ((size_t)bb * 512 + col) * 4096 + p;
        const float4 xv = *(const float4*)&auxA[idx];
        const float bv = auxB[col];
        float4 ov;
        ov.x = acc[m][n][0] + xv.x + bv;
        ov.y = acc[m][n][1] + xv.y + bv;
        ov.z = acc[m][n][2] + xv.z + bv;
        ov.w = acc[m][n][3] + xv.w + bv;
        *(float4*)&OUTF[idx] = ov;
      }
    }
  }
}

#define GEMM_ARGS const unsigned short* A, const unsigned short* B, unsigned short* C, \
                  float* OUTF, const float* auxA, const float* auxB, float* auxW, \
                  int M, int N, int K, float scale, size_t sA, size_t sB, size_t sC, int gx, int gy
#define GEMM_PASS A, B, C, OUTF, auxA, auxB, auxW, M, N, K, scale, sA, sB, sC, gx, gy

__global__ __launch_bounds__(512, 2) void k_qkproj(GEMM_ARGS){ gemm_body<1, 128>(GEMM_PASS); }
__global__ __launch_bounds__(512, 2) void k_vproj (GEMM_ARGS){ gemm_body<2, 128>(GEMM_PASS); }
__global__ __launch_bounds__(512, 2) void k_scores(GEMM_ARGS){ gemm_body<3, 256>(GEMM_PASS); }
__global__ __launch_bounds__(512, 2) void k_pv    (GEMM_ARGS){ gemm_body<4, 128>(GEMM_PASS); }
__global__ __launch_bounds__(512, 2) void k_oproj (GEMM_ARGS){ gemm_body<5, 128>(GEMM_PASS); }

// ---------------- rowsum reduce ----------------
__global__ __launch_bounds__(256) void rowsum_inv(const float* __restrict__ partial,
                                                  float* __restrict__ rinv){
  const int idx = blockIdx.x * 256 + threadIdx.x;   // 16384
  const int b = idx >> 12, q = idx & 4095;
  const float* p = partial + ((size_t)b * 64) * 4096 + q;
  float s = 0.f;
#pragma unroll
  for (int i = 0; i < 64; i++) s += p[(size_t)i * 4096];
  rinv[idx] = 1.f / s;
}

extern "C" void kernel_launch(void* const* d_in, const int* in_sizes, int n_in,
                              void* d_out, int out_size, void* d_ws, size_t ws_size,
                              hipStream_t stream) {
  const float* x     = (const float*)d_in[0];
  const float* mask  = (const float*)d_in[1];
  const float* gamma = (const float*)d_in[2];
  const float* beta  = (const float*)d_in[3];
  const float* Wq    = (const float*)d_in[4];
  const float* bq    = (const float*)d_in[5];
  const float* Wk    = (const float*)d_in[6];
  const float* bk    = (const float*)d_in[7];
  const float* Wv    = (const float*)d_in[8];
  const float* bv    = (const float*)d_in[9];
  const float* Wo    = (const float*)d_in[10];
  const float* bo    = (const float*)d_in[11];
  float* out = (float*)d_out;

  size_t off = 0;
  auto nxt = [&](size_t bytes) -> void* {
    void* p = (char*)d_ws + off;
    off += (bytes + 255) & ~(size_t)255;
    return p;
  };
  float* stats          = (float*)nxt(256 * sizeof(float));
  float* spart          = (float*)nxt(2048 * sizeof(float));
  float* partial        = (float*)nxt((size_t)4 * 64 * 4096 * 4);
  float* rinv           = (float*)nxt((size_t)16384 * 4);
  unsigned short* Wqb   = (unsigned short*)nxt((size_t)512 * 512 * 2);
  unsigned short* Wkb   = (unsigned short*)nxt((size_t)512 * 512 * 2);
  unsigned short* Wvb   = (unsigned short*)nxt((size_t)512 * 512 * 2);
  unsigned short* Wob   = (unsigned short*)nxt((size_t)512 * 512 * 2);
  unsigned short* hnt   = (unsigned short*)nxt((size_t)16384 * 512 * 2);
  unsigned short* qt    = (unsigned short*)nxt((size_t)16384 * 512 * 2);
  unsigned short* ktb   = (unsigned short*)nxt((size_t)16384 * 512 * 2);
  unsigned short* vcm   = (unsigned short*)nxt((size_t)16384 * 512 * 2);
  unsigned short* ot    = (unsigned short*)nxt((size_t)16384 * 512 * 2);
  unsigned short* P     = (unsigned short*)nxt((size_t)4 * 4096 * 4096 * 2);

  conv4<<<512, 256, 0, stream>>>(Wq, Wk, Wv, Wo, Wqb, Wkb, Wvb, Wob);

  gn_stats1<<<1024, 256, 0, stream>>>(x, spart);
  gn_stats2<<<1, 128, 0, stream>>>(spart, stats);
  gn_apply<<<dim3(128, 16, 4), 256, 0, stream>>>(x, stats, gamma, beta, hnt);

  // Q, K: [16384,512] = hn_t x W^T (+ per-col bias); gx=64, gy=4 -> 256
  k_qkproj<<<256, 512, 0, stream>>>(hnt, Wqb, qt, nullptr, bq, nullptr, nullptr,
                                    16384, 512, 512, 1.f, 0, 0, 0, 64, 4);
  k_qkproj<<<256, 512, 0, stream>>>(hnt, Wkb, ktb, nullptr, bk, nullptr, nullptr,
                                    16384, 512, 512, 1.f, 0, 0, 0, 64, 4);
  // V channel-major: v_cm[b][c][p] (+ per-row bias); gx=2, gy=32, gz=4 -> 256
  k_vproj<<<256, 512, 0, stream>>>(Wvb, hnt, vcm, nullptr, bv, nullptr, nullptr,
                                   512, 4096, 512, 1.f,
                                   0, (size_t)4096 * 512, (size_t)512 * 4096, 2, 32);
  // scores -> P_un = mask*exp(s*scale) (bf16) + row partial sums; gx=16, gy=16, gz=4 -> 1024
  k_scores<<<1024, 512, 0, stream>>>(qt, ktb, P, nullptr, mask, nullptr, partial,
                                     4096, 4096, 512, 0.044194173824159216f,
                                     (size_t)4096 * 512, (size_t)4096 * 512,
                                     (size_t)4096 * 4096, 16, 16);
  rowsum_inv<<<64, 256, 0, stream>>>(partial, rinv);
  // PV: ot[b][qi][c] = (P_un x v_cm^T) * rinv[qi]; gx=16, gy=4, gz=4 -> 256
  k_pv<<<256, 512, 0, stream>>>(P, vcm, ot, nullptr, rinv, nullptr, nullptr,
                                4096, 512, 4096, 1.f,
                                (size_t)4096 * 4096, (size_t)512 * 4096,
                                (size_t)4096 * 512, 16, 4);
  // O-projection + residual + bias -> fp32 out; gx=64, gy=4 -> 256
  k_oproj<<<256, 512, 0, stream>>>(ot, Wob, nullptr, out, x, bo, nullptr,
                                   16384, 512, 512, 1.f, 0, 0, 0, 64, 4);
}